// Round 2
// baseline (178.034 us; speedup 1.0000x reference)
//
#include <hip/hip_runtime.h>
#include <math.h>

#define NF 32
#define NDOF 29
#define BLOCK 256
#define SLOT_DW 20          // dwords per staged pose (80 B: 16-B aligned, ~conflict-free)

typedef float fx4 __attribute__((ext_vector_type(4)));   // native vector for nontemporal

// N = A @ B for 3x4 affines (row-major [r*4+c], implicit bottom row 0001)
__device__ __forceinline__ void amul(float* __restrict__ N,
                                     const float* __restrict__ A,
                                     const float* __restrict__ B) {
    #pragma unroll
    for (int r = 0; r < 3; ++r) {
        const float a0 = A[r*4+0], a1 = A[r*4+1], a2 = A[r*4+2], a3 = A[r*4+3];
        N[r*4+0] = a0*B[0] + a1*B[4] + a2*B[8];
        N[r*4+1] = a0*B[1] + a1*B[5] + a2*B[9];
        N[r*4+2] = a0*B[2] + a1*B[6] + a2*B[10];
        N[r*4+3] = a0*B[3] + a1*B[7] + a2*B[11] + a3;
    }
}

// DPP row_shr:D within 16-lane rows. Lanes whose source crosses the 8-lane
// group boundary get garbage/zero, but those lanes never consume the value
// (guarded by sub >= D). VALU pipe: replaces ds_bpermute (DS pipe + addr VGPR).
#define DPP_SHR(dst, srcv, CTRL)                                              \
    dst = __int_as_float(__builtin_amdgcn_update_dpp(                          \
        0, __float_as_int(srcv), (CTRL), 0xF, 0xF, true))

__global__ __launch_bounds__(BLOCK, 4) void fk_kernel(
    const float* __restrict__ ja,       // (B,29)
    const float* __restrict__ axes,     // (32,3)
    const float* __restrict__ origins,  // (32,4,4)
    const float* __restrict__ mmul,     // (2,)
    const float* __restrict__ moff,     // (2,)
    const int*   __restrict__ ctrl,     // (29,)
    const int*   __restrict__ msrc,     // (2,)
    const int*   __restrict__ mdst,     // (2,)
    const int*   __restrict__ types,    // (32,)
    float*       __restrict__ out,      // (B,32,4,4)
    int B)
{
    __shared__ float s_ax[NF][3];
    __shared__ float s_or[NF][12];
    __shared__ int   s_type[NF];
    __shared__ int   s_slot[NF];
    __shared__ float s_mult[NF];
    __shared__ float s_off[NF];
    __shared__ float s_stage[4][64 * SLOT_DW];   // per-wave staging (epilogue only)
    // s_ja aliases the stage buffer: live only between barrier 1 and barrier 2.
    float* const s_ja = &s_stage[0][0];          // 32*29 = 928 floats < 1280

    const int tid  = threadIdx.x;
    const int lane = tid & 63;
    const int wv   = tid >> 6;
    const int sub  = lane & 7;          // segment index within batch group

    // ---- coalesced stage of this block's 32x29 joint angles ----
    {
        const long jb   = (long)blockIdx.x * (32 * NDOF);
        const long jtot = (long)B * NDOF;
        #pragma unroll
        for (int i = 0; i < 4; ++i) {
            const int k = tid + i * BLOCK;
            if (k < 32 * NDOF) {
                const long g = jb + k;
                s_ja[k] = (g < jtot) ? ja[g] : 0.0f;
            }
        }
    }

    if (tid < NF) {
        const int f = tid;
        s_ax[f][0] = axes[f*3+0];
        s_ax[f][1] = axes[f*3+1];
        s_ax[f][2] = axes[f*3+2];
        #pragma unroll
        for (int i = 0; i < 12; ++i) s_or[f][i] = origins[f*16 + i];
        s_type[f] = types[f];
        int slot = -1;
        for (int j = 0; j < NDOF; ++j) if (ctrl[j] == f) slot = j;
        float mu = 1.0f, of = 0.0f;
        for (int m = 0; m < 2; ++m) {
            if (mdst[m] == f) {
                const int sf = msrc[m];
                for (int j = 0; j < NDOF; ++j) if (ctrl[j] == sf) slot = j;
                mu = mmul[m]; of = moff[m];
            }
        }
        s_slot[f] = slot; s_mult[f] = mu; s_off[f] = of;
    }
    __syncthreads();   // barrier 1: s_ja + frame constants ready

    const int  batl = tid >> 3;                          // batch within block
    const long bat  = (long)blockIdx.x * 32 + batl;
    const bool bok  = bat < (long)B;
    (void)bok;

    // ---- pass 1: local matrices for my 4 frames (angles from LDS) ----
    float M[4][12];
    #pragma unroll
    for (int j = 0; j < 4; ++j) {
        const int f    = 4*sub + j;
        const int slot = s_slot[f];
        float a = 0.0f;
        if (slot >= 0) a = fmaf(s_mult[f], s_ja[batl * NDOF + slot], s_off[f]);
        const float wx = a * s_ax[f][0];
        const float wy = a * s_ax[f][1];
        const float wz = a * s_ax[f][2];
        const int ty = s_type[f];
        float R0,R1,R2,R3,R4,R5,R6,R7,R8;
        if (ty == 1) {
            const float t2 = wx*wx + wy*wy + wz*wz;
            const float th = sqrtf(t2 + 1e-18f);
            const float inv = 1.0f / th;
            const float kx = wx*inv, ky = wy*inv, kz = wz*inv;
            float s, c;
            __sincosf(th, &s, &c);
            const float v = 1.0f - c;
            R0 = fmaf(v*kx, kx, c);
            R1 = v*kx*ky - s*kz;
            R2 = v*kx*kz + s*ky;
            R3 = v*kx*ky + s*kz;
            R4 = fmaf(v*ky, ky, c);
            R5 = v*ky*kz - s*kx;
            R6 = v*kx*kz - s*ky;
            R7 = v*ky*kz + s*kx;
            R8 = fmaf(v*kz, kz, c);
        } else {
            R0=1.f;R1=0.f;R2=0.f;R3=0.f;R4=1.f;R5=0.f;R6=0.f;R7=0.f;R8=1.f;
        }
        const float tx  = (ty == 2) ? wx : 0.0f;
        const float tyv = (ty == 2) ? wy : 0.0f;
        const float tz  = (ty == 2) ? wz : 0.0f;
        const float* O = s_or[f];
        #pragma unroll
        for (int r = 0; r < 3; ++r) {
            const float o0 = O[r*4+0], o1 = O[r*4+1], o2 = O[r*4+2], o3 = O[r*4+3];
            M[j][r*4+0] = o0*R0 + o1*R3 + o2*R6;
            M[j][r*4+1] = o0*R1 + o1*R4 + o2*R7;
            M[j][r*4+2] = o0*R2 + o1*R5 + o2*R8;
            M[j][r*4+3] = o0*tx + o1*tyv + o2*tz + o3;
        }
    }
    __syncthreads();   // barrier 2: s_ja dead; stage buffer free for epilogue

    // ---- segment product (lane 7: frames 28,29 only; 30,31 are leaves) ----
    float I[12];
    #pragma unroll
    for (int i = 0; i < 12; ++i) I[i] = M[0][i];
    #pragma unroll
    for (int j = 1; j < 4; ++j) {
        float N[12];
        amul(N, I, M[j]);
        const bool keep = !(sub == 7 && j >= 2);
        #pragma unroll
        for (int i = 0; i < 12; ++i) I[i] = keep ? N[i] : I[i];
    }

    // ---- 3-step inclusive scan over the 8 segments (DPP row_shr, VALU pipe) ----
    #define SCAN_STEP(D, CTRL)                                                \
    {                                                                         \
        float T[12], Nn[12];                                                  \
        _Pragma("unroll")                                                     \
        for (int i = 0; i < 12; ++i) DPP_SHR(T[i], I[i], CTRL);               \
        amul(Nn, T, I);                                                       \
        const bool use = (sub >= (D));                                        \
        _Pragma("unroll")                                                     \
        for (int i = 0; i < 12; ++i) I[i] = use ? Nn[i] : I[i];               \
    }
    SCAN_STEP(1, 0x111)
    SCAN_STEP(2, 0x112)
    SCAN_STEP(4, 0x114)
    #undef SCAN_STEP

    // ---- exclusive prefix E = I_{sub-1} (identity at sub 0), DPP shift ----
    float run[12];
    #pragma unroll
    for (int i = 0; i < 12; ++i) {
        float t;
        DPP_SHR(t, I[i], 0x111);
        const float idv = (i == 0 || i == 5 || i == 10) ? 1.0f : 0.0f;
        run[i] = (sub > 0) ? t : idv;
    }

    // ---- pass 2: chain poses in place; capture pose_10 at lane 2 ----
    float P10[12];
    #pragma unroll
    for (int i = 0; i < 12; ++i) P10[i] = run[i];
    #pragma unroll
    for (int j = 0; j < 4; ++j) {
        float N[12];
        amul(N, run, M[j]);
        const bool chain = !(sub == 7 && j >= 2);
        #pragma unroll
        for (int i = 0; i < 12; ++i) {
            M[j][i] = chain ? N[i] : M[j][i];
            run[i]  = chain ? N[i] : run[i];
        }
        if (j == 2 && sub == 2) {
            #pragma unroll
            for (int i = 0; i < 12; ++i) P10[i] = N[i];   // frame 10
        }
    }
    // broadcast pose_10 from sublane 2 of each 8-lane group:
    // ds_swizzle BitMode offset 0x58 = (xor 0)<<10 | (or 2)<<5 | (and 0x18)
    // -> src lane = (lane & 0x18) | 2 within each 32-lane half.
    #pragma unroll
    for (int i = 0; i < 12; ++i)
        P10[i] = __int_as_float(
            __builtin_amdgcn_ds_swizzle(__float_as_int(P10[i]), 0x58));
    #pragma unroll
    for (int j = 2; j < 4; ++j) {
        float N[12];
        amul(N, P10, M[j]);
        #pragma unroll
        for (int i = 0; i < 12; ++i) M[j][i] = (sub == 7) ? N[i] : M[j][i];
    }

    // ---- intra-wave LDS transpose + fully-coalesced full-line stores ----
    float* const st = s_stage[wv];
    const long wbat0 = (long)blockIdx.x * 32 + wv * 8;
    fx4* const out4 = (fx4*)out;
    const int row = lane & 3;

    #pragma unroll
    for (int j = 0; j < 4; ++j) {
        float4* wp = (float4*)&st[lane * SLOT_DW];
        wp[0] = make_float4(M[j][0], M[j][1], M[j][2],  M[j][3]);
        wp[1] = make_float4(M[j][4], M[j][5], M[j][6],  M[j][7]);
        wp[2] = make_float4(M[j][8], M[j][9], M[j][10], M[j][11]);
        wp[3] = make_float4(0.0f, 0.0f, 0.0f, 1.0f);
        __builtin_amdgcn_wave_barrier();   // DS is in-order within a wave
        #pragma unroll
        for (int m = 0; m < 4; ++m) {
            const int  slot = m * 16 + (lane >> 2);
            const fx4  v    = *(const fx4*)&st[slot * SLOT_DW + row * 4];
            const long bb   = wbat0 + (slot >> 3);
            const int  fr   = 4 * (slot & 7) + j;
            if (bb < (long)B)   // nontemporal: 128 MiB stream >> 4 MiB L2/XCD
                __builtin_nontemporal_store(v, &out4[bb * 128 + fr * 4 + row]);
        }
        __builtin_amdgcn_wave_barrier();
    }
}

extern "C" void kernel_launch(void* const* d_in, const int* in_sizes, int n_in,
                              void* d_out, int out_size, void* d_ws, size_t ws_size,
                              hipStream_t stream) {
    const float* ja   = (const float*)d_in[0];
    const float* axes = (const float*)d_in[1];
    const float* orig = (const float*)d_in[2];
    const float* mmul = (const float*)d_in[3];
    const float* moff = (const float*)d_in[4];
    const int*   ctrl = (const int*)d_in[5];
    const int*   msrc = (const int*)d_in[6];
    const int*   mdst = (const int*)d_in[7];
    const int*   typs = (const int*)d_in[8];
    float* out = (float*)d_out;

    const int B = in_sizes[0] / NDOF;
    const int grid = (B + 31) / 32;     // 32 batches per block (8 lanes/batch)
    fk_kernel<<<grid, BLOCK, 0, stream>>>(ja, axes, orig, mmul, moff,
                                          ctrl, msrc, mdst, typs, out, B);
}

// Round 3
// 173.652 us; speedup vs baseline: 1.0252x; 1.0252x over previous
//
#include <hip/hip_runtime.h>
#include <math.h>

#define NF 32
#define NDOF 29
#define BLOCK 256
#define SLOT_DW 20          // dwords per staged pose (80 B: 16-B aligned, ~conflict-free)

// N = A @ B for 3x4 affines (row-major [r*4+c], implicit bottom row 0001)
__device__ __forceinline__ void amul(float* __restrict__ N,
                                     const float* __restrict__ A,
                                     const float* __restrict__ B) {
    #pragma unroll
    for (int r = 0; r < 3; ++r) {
        const float a0 = A[r*4+0], a1 = A[r*4+1], a2 = A[r*4+2], a3 = A[r*4+3];
        N[r*4+0] = a0*B[0] + a1*B[4] + a2*B[8];
        N[r*4+1] = a0*B[1] + a1*B[5] + a2*B[9];
        N[r*4+2] = a0*B[2] + a1*B[6] + a2*B[10];
        N[r*4+3] = a0*B[3] + a1*B[7] + a2*B[11] + a3;
    }
}

// DPP row_shr:D within 16-lane rows. Lanes whose source would cross the
// 8-lane group boundary never consume the value (guarded by sub >= D).
// VALU pipe: replaces ds_bpermute (DS pipe + addr VGPR + lgkm wait).
#define DPP_SHR(dst, srcv, CTRL)                                              \
    dst = __int_as_float(__builtin_amdgcn_update_dpp(                          \
        0, __float_as_int(srcv), (CTRL), 0xF, 0xF, true))

__global__ __launch_bounds__(BLOCK) void fk_kernel(
    const float* __restrict__ ja,       // (B,29)
    const float* __restrict__ axes,     // (32,3)
    const float* __restrict__ origins,  // (32,4,4)
    const float* __restrict__ mmul,     // (2,)
    const float* __restrict__ moff,     // (2,)
    const int*   __restrict__ ctrl,     // (29,)
    const int*   __restrict__ msrc,     // (2,)
    const int*   __restrict__ mdst,     // (2,)
    const int*   __restrict__ types,    // (32,)
    float*       __restrict__ out,      // (B,32,4,4)
    int B)
{
    __shared__ float s_ax[NF][3];
    __shared__ float s_or[NF][12];
    __shared__ int   s_type[NF];
    __shared__ int   s_slot[NF];
    __shared__ float s_mult[NF];
    __shared__ float s_off[NF];
    __shared__ float s_stage[4][64 * SLOT_DW];   // per-wave staging (epilogue only)
    // s_ja aliases the stage buffer: live only between barrier 1 and barrier 2.
    float* const s_ja = &s_stage[0][0];          // 32*29 = 928 floats < 1280

    const int tid  = threadIdx.x;
    const int lane = tid & 63;
    const int wv   = tid >> 6;
    const int sub  = lane & 7;          // segment index within batch group

    // ---- coalesced stage of this block's 32x29 joint angles ----
    {
        const long jb   = (long)blockIdx.x * (32 * NDOF);
        const long jtot = (long)B * NDOF;
        #pragma unroll
        for (int i = 0; i < 4; ++i) {
            const int k = tid + i * BLOCK;
            if (k < 32 * NDOF) {
                const long g = jb + k;
                s_ja[k] = (g < jtot) ? ja[g] : 0.0f;
            }
        }
    }

    if (tid < NF) {
        const int f = tid;
        s_ax[f][0] = axes[f*3+0];
        s_ax[f][1] = axes[f*3+1];
        s_ax[f][2] = axes[f*3+2];
        #pragma unroll
        for (int i = 0; i < 12; ++i) s_or[f][i] = origins[f*16 + i];
        s_type[f] = types[f];
        int slot = -1;
        for (int j = 0; j < NDOF; ++j) if (ctrl[j] == f) slot = j;
        float mu = 1.0f, of = 0.0f;
        for (int m = 0; m < 2; ++m) {
            if (mdst[m] == f) {
                const int sf = msrc[m];
                for (int j = 0; j < NDOF; ++j) if (ctrl[j] == sf) slot = j;
                mu = mmul[m]; of = moff[m];
            }
        }
        s_slot[f] = slot; s_mult[f] = mu; s_off[f] = of;
    }
    __syncthreads();   // barrier 1: s_ja + frame constants ready

    const int  batl = tid >> 3;                          // batch within block
    const long bat  = (long)blockIdx.x * 32 + batl;

    // ---- pass 1: local matrices for my 4 frames (angles from LDS) ----
    float M[4][12];
    #pragma unroll
    for (int j = 0; j < 4; ++j) {
        const int f    = 4*sub + j;
        const int slot = s_slot[f];
        float a = 0.0f;
        if (slot >= 0) a = fmaf(s_mult[f], s_ja[batl * NDOF + slot], s_off[f]);
        const float wx = a * s_ax[f][0];
        const float wy = a * s_ax[f][1];
        const float wz = a * s_ax[f][2];
        const int ty = s_type[f];
        float R0,R1,R2,R3,R4,R5,R6,R7,R8;
        if (ty == 1) {
            const float t2 = wx*wx + wy*wy + wz*wz;
            const float th = sqrtf(t2 + 1e-18f);
            const float inv = 1.0f / th;
            const float kx = wx*inv, ky = wy*inv, kz = wz*inv;
            float s, c;
            __sincosf(th, &s, &c);
            const float v = 1.0f - c;
            R0 = fmaf(v*kx, kx, c);
            R1 = v*kx*ky - s*kz;
            R2 = v*kx*kz + s*ky;
            R3 = v*kx*ky + s*kz;
            R4 = fmaf(v*ky, ky, c);
            R5 = v*ky*kz - s*kx;
            R6 = v*kx*kz - s*ky;
            R7 = v*ky*kz + s*kx;
            R8 = fmaf(v*kz, kz, c);
        } else {
            R0=1.f;R1=0.f;R2=0.f;R3=0.f;R4=1.f;R5=0.f;R6=0.f;R7=0.f;R8=1.f;
        }
        const float tx  = (ty == 2) ? wx : 0.0f;
        const float tyv = (ty == 2) ? wy : 0.0f;
        const float tz  = (ty == 2) ? wz : 0.0f;
        const float* O = s_or[f];
        #pragma unroll
        for (int r = 0; r < 3; ++r) {
            const float o0 = O[r*4+0], o1 = O[r*4+1], o2 = O[r*4+2], o3 = O[r*4+3];
            M[j][r*4+0] = o0*R0 + o1*R3 + o2*R6;
            M[j][r*4+1] = o0*R1 + o1*R4 + o2*R7;
            M[j][r*4+2] = o0*R2 + o1*R5 + o2*R8;
            M[j][r*4+3] = o0*tx + o1*tyv + o2*tz + o3;
        }
    }
    __syncthreads();   // barrier 2: s_ja dead; stage buffer free for epilogue

    // ---- segment product (lane 7: frames 28,29 only; 30,31 are leaves) ----
    float I[12];
    #pragma unroll
    for (int i = 0; i < 12; ++i) I[i] = M[0][i];
    #pragma unroll
    for (int j = 1; j < 4; ++j) {
        float N[12];
        amul(N, I, M[j]);
        const bool keep = !(sub == 7 && j >= 2);
        #pragma unroll
        for (int i = 0; i < 12; ++i) I[i] = keep ? N[i] : I[i];
    }

    // ---- 3-step inclusive scan over the 8 segments (DPP row_shr, VALU pipe) ----
    #define SCAN_STEP(D, CTRL)                                                \
    {                                                                         \
        float T[12], Nn[12];                                                  \
        _Pragma("unroll")                                                     \
        for (int i = 0; i < 12; ++i) DPP_SHR(T[i], I[i], CTRL);               \
        amul(Nn, T, I);                                                       \
        const bool use = (sub >= (D));                                        \
        _Pragma("unroll")                                                     \
        for (int i = 0; i < 12; ++i) I[i] = use ? Nn[i] : I[i];               \
    }
    SCAN_STEP(1, 0x111)
    SCAN_STEP(2, 0x112)
    SCAN_STEP(4, 0x114)
    #undef SCAN_STEP

    // ---- exclusive prefix E = I_{sub-1} (identity at sub 0), DPP shift ----
    float run[12];
    #pragma unroll
    for (int i = 0; i < 12; ++i) {
        float t;
        DPP_SHR(t, I[i], 0x111);
        const float idv = (i == 0 || i == 5 || i == 10) ? 1.0f : 0.0f;
        run[i] = (sub > 0) ? t : idv;
    }

    // ---- pass 2: chain poses in place; capture pose_10 at lane 2 ----
    float P10[12];
    #pragma unroll
    for (int i = 0; i < 12; ++i) P10[i] = run[i];
    #pragma unroll
    for (int j = 0; j < 4; ++j) {
        float N[12];
        amul(N, run, M[j]);
        const bool chain = !(sub == 7 && j >= 2);
        #pragma unroll
        for (int i = 0; i < 12; ++i) {
            M[j][i] = chain ? N[i] : M[j][i];
            run[i]  = chain ? N[i] : run[i];
        }
        if (j == 2 && sub == 2) {
            #pragma unroll
            for (int i = 0; i < 12; ++i) P10[i] = N[i];   // frame 10
        }
    }
    // broadcast pose_10 from sublane 2 of each 8-lane group:
    // ds_swizzle BitMode offset 0x58 = (xor 0)<<10 | (or 2)<<5 | (and 0x18)
    // -> src lane = (lane & 0x18) | 2 within each 32-lane half.
    #pragma unroll
    for (int i = 0; i < 12; ++i)
        P10[i] = __int_as_float(
            __builtin_amdgcn_ds_swizzle(__float_as_int(P10[i]), 0x58));
    #pragma unroll
    for (int j = 2; j < 4; ++j) {
        float N[12];
        amul(N, P10, M[j]);
        #pragma unroll
        for (int i = 0; i < 12; ++i) M[j][i] = (sub == 7) ? N[i] : M[j][i];
    }

    // ---- intra-wave LDS transpose + fully-coalesced full-line stores ----
    float* const st = s_stage[wv];
    const long wbat0 = (long)blockIdx.x * 32 + wv * 8;
    float4* const out4 = (float4*)out;
    const int row = lane & 3;

    #pragma unroll
    for (int j = 0; j < 4; ++j) {
        float4* wp = (float4*)&st[lane * SLOT_DW];
        wp[0] = make_float4(M[j][0], M[j][1], M[j][2],  M[j][3]);
        wp[1] = make_float4(M[j][4], M[j][5], M[j][6],  M[j][7]);
        wp[2] = make_float4(M[j][8], M[j][9], M[j][10], M[j][11]);
        wp[3] = make_float4(0.0f, 0.0f, 0.0f, 1.0f);
        __builtin_amdgcn_wave_barrier();   // DS is in-order within a wave
        #pragma unroll
        for (int m = 0; m < 4; ++m) {
            const int  slot = m * 16 + (lane >> 2);
            const float4 v  = *(const float4*)&st[slot * SLOT_DW + row * 4];
            const long bb   = wbat0 + (slot >> 3);
            const int  fr   = 4 * (slot & 7) + j;
            if (bb < (long)B)
                out4[bb * 128 + fr * 4 + row] = v;   // 4-lane cluster = 1 full line
        }
        __builtin_amdgcn_wave_barrier();
    }
}

extern "C" void kernel_launch(void* const* d_in, const int* in_sizes, int n_in,
                              void* d_out, int out_size, void* d_ws, size_t ws_size,
                              hipStream_t stream) {
    const float* ja   = (const float*)d_in[0];
    const float* axes = (const float*)d_in[1];
    const float* orig = (const float*)d_in[2];
    const float* mmul = (const float*)d_in[3];
    const float* moff = (const float*)d_in[4];
    const int*   ctrl = (const int*)d_in[5];
    const int*   msrc = (const int*)d_in[6];
    const int*   mdst = (const int*)d_in[7];
    const int*   typs = (const int*)d_in[8];
    float* out = (float*)d_out;

    const int B = in_sizes[0] / NDOF;
    const int grid = (B + 31) / 32;     // 32 batches per block (8 lanes/batch)
    fk_kernel<<<grid, BLOCK, 0, stream>>>(ja, axes, orig, mmul, moff,
                                          ctrl, msrc, mdst, typs, out, B);
}

// Round 4
// 168.052 us; speedup vs baseline: 1.0594x; 1.0333x over previous
//
#include <hip/hip_runtime.h>
#include <math.h>

#define NF 32
#define NDOF 29
#define BLOCK 256
#define SLOT_DW 20          // dwords per staged pose (80 B: 16-B aligned, ~conflict-free)

// N = A @ B for 3x4 affines (row-major [r*4+c], implicit bottom row 0001)
__device__ __forceinline__ void amul(float* __restrict__ N,
                                     const float* __restrict__ A,
                                     const float* __restrict__ B) {
    #pragma unroll
    for (int r = 0; r < 3; ++r) {
        const float a0 = A[r*4+0], a1 = A[r*4+1], a2 = A[r*4+2], a3 = A[r*4+3];
        N[r*4+0] = a0*B[0] + a1*B[4] + a2*B[8];
        N[r*4+1] = a0*B[1] + a1*B[5] + a2*B[9];
        N[r*4+2] = a0*B[2] + a1*B[6] + a2*B[10];
        N[r*4+3] = a0*B[3] + a1*B[7] + a2*B[11] + a3;
    }
}

__global__ __launch_bounds__(BLOCK) void fk_kernel(
    const float* __restrict__ ja,       // (B,29)
    const float* __restrict__ axes,     // (32,3)
    const float* __restrict__ origins,  // (32,4,4)
    const float* __restrict__ mmul,     // (2,)
    const float* __restrict__ moff,     // (2,)
    const int*   __restrict__ ctrl,     // (29,)
    const int*   __restrict__ msrc,     // (2,)
    const int*   __restrict__ mdst,     // (2,)
    const int*   __restrict__ types,    // (32,)
    float*       __restrict__ out,      // (B,32,4,4)
    int B)
{
    __shared__ float s_ax[NF][3];
    __shared__ float s_or[NF][12];
    __shared__ int   s_type[NF];
    __shared__ int   s_slot[NF];
    __shared__ float s_mult[NF];
    __shared__ float s_off[NF];
    __shared__ float s_stage[4][64 * SLOT_DW];   // per-wave staging

    const int tid  = threadIdx.x;
    const int lane = tid & 63;
    const int wv   = tid >> 6;
    const int sub  = lane & 7;          // segment index within batch group
    const int grp  = lane & ~7;         // 8-lane group base within wave

    if (tid < NF) {
        const int f = tid;
        s_ax[f][0] = axes[f*3+0];
        s_ax[f][1] = axes[f*3+1];
        s_ax[f][2] = axes[f*3+2];
        #pragma unroll
        for (int i = 0; i < 12; ++i) s_or[f][i] = origins[f*16 + i];
        s_type[f] = types[f];
        int slot = -1;
        for (int j = 0; j < NDOF; ++j) if (ctrl[j] == f) slot = j;
        float mu = 1.0f, of = 0.0f;
        for (int m = 0; m < 2; ++m) {
            if (mdst[m] == f) {
                const int sf = msrc[m];
                for (int j = 0; j < NDOF; ++j) if (ctrl[j] == sf) slot = j;
                mu = mmul[m]; of = moff[m];
            }
        }
        s_slot[f] = slot; s_mult[f] = mu; s_off[f] = of;
    }
    __syncthreads();   // only block barrier; precedes all global stores

    const long bat = (long)blockIdx.x * 32 + (tid >> 3);
    const bool bok = bat < (long)B;

    // ---- cache my 4 joint angles (loads cluster, latency overlaps) ----
    float ang[4];
    #pragma unroll
    for (int j = 0; j < 4; ++j) {
        const int f    = 4*sub + j;
        const int slot = s_slot[f];
        ang[j] = (slot >= 0 && bok)
               ? fmaf(s_mult[f], ja[bat * NDOF + slot], s_off[f]) : 0.0f;
    }

    // local-matrix builder: L = origins[f] @ motion(f, ang[j]).
    // Called twice per frame (pass1 + pass2) so no M[4][12] stays live:
    // trades ~280 VALU ops/thread for ~48 VGPRs (occupancy lever).
    auto build = [&](int j, float* __restrict__ L) {
        const int f = 4*sub + j;
        const float a  = ang[j];
        const float wx = a * s_ax[f][0];
        const float wy = a * s_ax[f][1];
        const float wz = a * s_ax[f][2];
        const int ty = s_type[f];
        float R0,R1,R2,R3,R4,R5,R6,R7,R8;
        if (ty == 1) {
            const float t2 = wx*wx + wy*wy + wz*wz;
            const float th = sqrtf(t2 + 1e-18f);
            const float inv = 1.0f / th;
            const float kx = wx*inv, ky = wy*inv, kz = wz*inv;
            float s, c;
            __sincosf(th, &s, &c);
            const float v = 1.0f - c;
            R0 = fmaf(v*kx, kx, c);
            R1 = v*kx*ky - s*kz;
            R2 = v*kx*kz + s*ky;
            R3 = v*kx*ky + s*kz;
            R4 = fmaf(v*ky, ky, c);
            R5 = v*ky*kz - s*kx;
            R6 = v*kx*kz - s*ky;
            R7 = v*ky*kz + s*kx;
            R8 = fmaf(v*kz, kz, c);
        } else {
            R0=1.f;R1=0.f;R2=0.f;R3=0.f;R4=1.f;R5=0.f;R6=0.f;R7=0.f;R8=1.f;
        }
        const float tx  = (ty == 2) ? wx : 0.0f;
        const float tyv = (ty == 2) ? wy : 0.0f;
        const float tz  = (ty == 2) ? wz : 0.0f;
        const float* O = s_or[f];
        #pragma unroll
        for (int r = 0; r < 3; ++r) {
            const float o0 = O[r*4+0], o1 = O[r*4+1], o2 = O[r*4+2], o3 = O[r*4+3];
            L[r*4+0] = o0*R0 + o1*R3 + o2*R6;
            L[r*4+1] = o0*R1 + o1*R4 + o2*R7;
            L[r*4+2] = o0*R2 + o1*R5 + o2*R8;
            L[r*4+3] = o0*tx + o1*tyv + o2*tz + o3;
        }
    };

    // ---- pass 1: segment product, locals folded in immediately ----
    // (lane 7: frames 28,29 only; 30,31 are leaves)
    float I[12];
    {
        float L[12];
        build(0, L);
        #pragma unroll
        for (int i = 0; i < 12; ++i) I[i] = L[i];
        #pragma unroll
        for (int j = 1; j < 4; ++j) {
            build(j, L);
            float N[12];
            amul(N, I, L);
            const bool keep = !(sub == 7 && j >= 2);
            #pragma unroll
            for (int i = 0; i < 12; ++i) I[i] = keep ? N[i] : I[i];
        }
    }

    // ---- 3-step inclusive scan over the 8 segments (shuffle, in-group) ----
    #pragma unroll
    for (int d = 1; d <= 4; d <<= 1) {
        const int src = grp | ((sub - d) & 7);
        float T[12];
        #pragma unroll
        for (int i = 0; i < 12; ++i) T[i] = __shfl(I[i], src, 64);
        float N[12];
        amul(N, T, I);
        const bool use = (sub >= d);
        #pragma unroll
        for (int i = 0; i < 12; ++i) I[i] = use ? N[i] : I[i];
    }

    // ---- exclusive prefix run = I_{sub-1} (identity at sub 0) ----
    const float ID[12] = {1,0,0,0, 0,1,0,0, 0,0,1,0};
    float run[12];
    {
        const int src = grp | ((sub - 1) & 7);
        #pragma unroll
        for (int i = 0; i < 12; ++i) {
            const float t = __shfl(I[i], src, 64);
            run[i] = (sub > 0) ? t : ID[i];
        }
    }

    // ---- pass 2 (fused with store): rebuild local, chain, stage, store ----
    float* const st = s_stage[wv];
    const long wbat0 = (long)blockIdx.x * 32 + wv * 8;
    float4* const out4 = (float4*)out;
    const int row = lane & 3;

    float P10[12];
    #pragma unroll
    for (int i = 0; i < 12; ++i) P10[i] = 0.0f;

    #pragma unroll
    for (int j = 0; j < 4; ++j) {
        float L[12];
        build(j, L);
        float N[12];
        amul(N, run, L);

        // frame 10 is (sub==2, j==2); broadcast its pose within each group
        if (j == 2) {
            #pragma unroll
            for (int i = 0; i < 12; ++i) P10[i] = __shfl(N[i], grp | 2, 64);
        }

        float pose[12];
        if (j < 2) {
            #pragma unroll
            for (int i = 0; i < 12; ++i) pose[i] = N[i];
        } else {
            // leaves 30,31 live at sub==7, j==2/3: pose = pose10 @ L
            float Lf[12];
            amul(Lf, P10, L);
            #pragma unroll
            for (int i = 0; i < 12; ++i) pose[i] = (sub == 7) ? Lf[i] : N[i];
        }

        const bool chain = !(sub == 7 && j >= 2);
        #pragma unroll
        for (int i = 0; i < 12; ++i) run[i] = chain ? N[i] : run[i];

        // stage this j's pose via LDS transpose; full-line coalesced stores
        float4* wp = (float4*)&st[lane * SLOT_DW];
        wp[0] = make_float4(pose[0], pose[1], pose[2],  pose[3]);
        wp[1] = make_float4(pose[4], pose[5], pose[6],  pose[7]);
        wp[2] = make_float4(pose[8], pose[9], pose[10], pose[11]);
        wp[3] = make_float4(0.0f, 0.0f, 0.0f, 1.0f);
        __builtin_amdgcn_wave_barrier();   // DS is in-order within a wave
        #pragma unroll
        for (int m = 0; m < 4; ++m) {
            const int  slot = m * 16 + (lane >> 2);
            const float4 v  = *(const float4*)&st[slot * SLOT_DW + row * 4];
            const long bb   = wbat0 + (slot >> 3);
            const int  fr   = 4 * (slot & 7) + j;
            if (bb < (long)B)
                out4[bb * 128 + fr * 4 + row] = v;   // 4-lane cluster = 1 full line
        }
        __builtin_amdgcn_wave_barrier();
    }
}

extern "C" void kernel_launch(void* const* d_in, const int* in_sizes, int n_in,
                              void* d_out, int out_size, void* d_ws, size_t ws_size,
                              hipStream_t stream) {
    const float* ja   = (const float*)d_in[0];
    const float* axes = (const float*)d_in[1];
    const float* orig = (const float*)d_in[2];
    const float* mmul = (const float*)d_in[3];
    const float* moff = (const float*)d_in[4];
    const int*   ctrl = (const int*)d_in[5];
    const int*   msrc = (const int*)d_in[6];
    const int*   mdst = (const int*)d_in[7];
    const int*   typs = (const int*)d_in[8];
    float* out = (float*)d_out;

    const int B = in_sizes[0] / NDOF;
    const int grid = (B + 31) / 32;     // 32 batches per block (8 lanes/batch)
    fk_kernel<<<grid, BLOCK, 0, stream>>>(ja, axes, orig, mmul, moff,
                                          ctrl, msrc, mdst, typs, out, B);
}

// Round 5
// 163.913 us; speedup vs baseline: 1.0861x; 1.0252x over previous
//
#include <hip/hip_runtime.h>
#include <math.h>

#define NF 32
#define NDOF 29
#define BLOCK 256
#define SLOT_DW 20          // dwords per staged pose (80 B: 16-B aligned, ~conflict-free)

// N = A @ B for 3x4 affines (row-major [r*4+c], implicit bottom row 0001)
__device__ __forceinline__ void amul(float* __restrict__ N,
                                     const float* __restrict__ A,
                                     const float* __restrict__ B) {
    #pragma unroll
    for (int r = 0; r < 3; ++r) {
        const float a0 = A[r*4+0], a1 = A[r*4+1], a2 = A[r*4+2], a3 = A[r*4+3];
        N[r*4+0] = a0*B[0] + a1*B[4] + a2*B[8];
        N[r*4+1] = a0*B[1] + a1*B[5] + a2*B[9];
        N[r*4+2] = a0*B[2] + a1*B[6] + a2*B[10];
        N[r*4+3] = a0*B[3] + a1*B[7] + a2*B[11] + a3;
    }
}

__global__ __launch_bounds__(BLOCK) void fk_kernel(
    const float* __restrict__ ja,       // (B,29)
    const float* __restrict__ axes,     // (32,3)
    const float* __restrict__ origins,  // (32,4,4)
    const float* __restrict__ mmul,     // (2,)
    const float* __restrict__ moff,     // (2,)
    const int*   __restrict__ ctrl,     // (29,)
    const int*   __restrict__ msrc,     // (2,)
    const int*   __restrict__ mdst,     // (2,)
    const int*   __restrict__ types,    // (32,)
    float*       __restrict__ out,      // (B,32,4,4)
    int B)
{
    __shared__ float s_ax[NF][3];
    __shared__ float s_or[NF][12];
    __shared__ int   s_type[NF];
    __shared__ int   s_slot[NF];
    __shared__ float s_mult[NF];
    __shared__ float s_off[NF];
    __shared__ float s_stage[4][64 * SLOT_DW];   // per-wave staging

    const int tid  = threadIdx.x;
    const int lane = tid & 63;
    const int wv   = tid >> 6;
    const int sub  = lane & 7;          // segment index within batch group
    const int grp  = lane & ~7;         // 8-lane group base within wave

    if (tid < NF) {
        const int f = tid;
        s_ax[f][0] = axes[f*3+0];
        s_ax[f][1] = axes[f*3+1];
        s_ax[f][2] = axes[f*3+2];
        #pragma unroll
        for (int i = 0; i < 12; ++i) s_or[f][i] = origins[f*16 + i];
        s_type[f] = types[f];
        int slot = -1;
        for (int j = 0; j < NDOF; ++j) if (ctrl[j] == f) slot = j;
        float mu = 1.0f, of = 0.0f;
        for (int m = 0; m < 2; ++m) {
            if (mdst[m] == f) {
                const int sf = msrc[m];
                for (int j = 0; j < NDOF; ++j) if (ctrl[j] == sf) slot = j;
                mu = mmul[m]; of = moff[m];
            }
        }
        s_slot[f] = slot; s_mult[f] = mu; s_off[f] = of;
    }
    __syncthreads();   // only block barrier; precedes all global stores

    const long bat = (long)blockIdx.x * 32 + (tid >> 3);   // this group's batch
    const bool bok = bat < (long)B;

    // ---- pass 1: local matrices for my 4 frames ----
    float M[4][12];
    #pragma unroll
    for (int j = 0; j < 4; ++j) {
        const int f    = 4*sub + j;
        const int slot = s_slot[f];
        float a = 0.0f;
        if (slot >= 0 && bok) a = fmaf(s_mult[f], ja[bat * NDOF + slot], s_off[f]);
        const float wx = a * s_ax[f][0];
        const float wy = a * s_ax[f][1];
        const float wz = a * s_ax[f][2];
        const int ty = s_type[f];
        float R0,R1,R2,R3,R4,R5,R6,R7,R8;
        if (ty == 1) {
            const float t2 = wx*wx + wy*wy + wz*wz;
            const float th = sqrtf(t2 + 1e-18f);
            const float inv = 1.0f / th;
            const float kx = wx*inv, ky = wy*inv, kz = wz*inv;
            float s, c;
            __sincosf(th, &s, &c);
            const float v = 1.0f - c;
            R0 = fmaf(v*kx, kx, c);
            R1 = v*kx*ky - s*kz;
            R2 = v*kx*kz + s*ky;
            R3 = v*kx*ky + s*kz;
            R4 = fmaf(v*ky, ky, c);
            R5 = v*ky*kz - s*kx;
            R6 = v*kx*kz - s*ky;
            R7 = v*ky*kz + s*kx;
            R8 = fmaf(v*kz, kz, c);
        } else {
            R0=1.f;R1=0.f;R2=0.f;R3=0.f;R4=1.f;R5=0.f;R6=0.f;R7=0.f;R8=1.f;
        }
        const float tx  = (ty == 2) ? wx : 0.0f;
        const float tyv = (ty == 2) ? wy : 0.0f;
        const float tz  = (ty == 2) ? wz : 0.0f;
        const float* O = s_or[f];
        #pragma unroll
        for (int r = 0; r < 3; ++r) {
            const float o0 = O[r*4+0], o1 = O[r*4+1], o2 = O[r*4+2], o3 = O[r*4+3];
            M[j][r*4+0] = o0*R0 + o1*R3 + o2*R6;
            M[j][r*4+1] = o0*R1 + o1*R4 + o2*R7;
            M[j][r*4+2] = o0*R2 + o1*R5 + o2*R8;
            M[j][r*4+3] = o0*tx + o1*tyv + o2*tz + o3;
        }
    }

    // ---- segment product (lane 7: frames 28,29 only; 30,31 are leaves) ----
    float I[12];
    #pragma unroll
    for (int i = 0; i < 12; ++i) I[i] = M[0][i];
    #pragma unroll
    for (int j = 1; j < 4; ++j) {
        float N[12];
        amul(N, I, M[j]);
        const bool keep = !(sub == 7 && j >= 2);
        #pragma unroll
        for (int i = 0; i < 12; ++i) I[i] = keep ? N[i] : I[i];
    }

    // ---- 3-step inclusive scan over the 8 segments (shuffle, in-group) ----
    #pragma unroll
    for (int d = 1; d <= 4; d <<= 1) {
        const int src = grp | ((sub - d) & 7);
        float T[12];
        #pragma unroll
        for (int i = 0; i < 12; ++i) T[i] = __shfl(I[i], src, 64);
        float N[12];
        amul(N, T, I);
        const bool use = (sub >= d);
        #pragma unroll
        for (int i = 0; i < 12; ++i) I[i] = use ? N[i] : I[i];
    }

    // ---- exclusive prefix E = I_{sub-1} (identity at sub 0) ----
    const float ID[12] = {1,0,0,0, 0,1,0,0, 0,0,1,0};
    float run[12];
    {
        const int src = grp | ((sub - 1) & 7);
        #pragma unroll
        for (int i = 0; i < 12; ++i) {
            const float t = __shfl(I[i], src, 64);
            run[i] = (sub > 0) ? t : ID[i];
        }
    }

    // ---- pass 2: chain poses in place; capture pose_10 at lane 2 ----
    float P10[12];
    #pragma unroll
    for (int i = 0; i < 12; ++i) P10[i] = run[i];
    #pragma unroll
    for (int j = 0; j < 4; ++j) {
        float N[12];
        amul(N, run, M[j]);
        const bool chain = !(sub == 7 && j >= 2);
        #pragma unroll
        for (int i = 0; i < 12; ++i) {
            M[j][i] = chain ? N[i] : M[j][i];
            run[i]  = chain ? N[i] : run[i];
        }
        if (j == 2 && sub == 2) {
            #pragma unroll
            for (int i = 0; i < 12; ++i) P10[i] = N[i];   // frame 10
        }
    }
    // broadcast pose_10 from sublane 2; compose leaves 30,31 on lane 7
    #pragma unroll
    for (int i = 0; i < 12; ++i) P10[i] = __shfl(P10[i], grp | 2, 64);
    #pragma unroll
    for (int j = 2; j < 4; ++j) {
        float N[12];
        amul(N, P10, M[j]);
        #pragma unroll
        for (int i = 0; i < 12; ++i) M[j][i] = (sub == 7) ? N[i] : M[j][i];
    }

    // ---- intra-wave LDS transpose + fully-coalesced full-line stores ----
    float* const st = s_stage[wv];
    const long wbat0 = (long)blockIdx.x * 32 + wv * 8;
    float4* const out4 = (float4*)out;
    const int row = lane & 3;

    #pragma unroll
    for (int j = 0; j < 4; ++j) {
        float4* wp = (float4*)&st[lane * SLOT_DW];
        wp[0] = make_float4(M[j][0], M[j][1], M[j][2],  M[j][3]);
        wp[1] = make_float4(M[j][4], M[j][5], M[j][6],  M[j][7]);
        wp[2] = make_float4(M[j][8], M[j][9], M[j][10], M[j][11]);
        wp[3] = make_float4(0.0f, 0.0f, 0.0f, 1.0f);
        __builtin_amdgcn_wave_barrier();   // DS is in-order within a wave
        #pragma unroll
        for (int m = 0; m < 4; ++m) {
            const int  slot = m * 16 + (lane >> 2);
            const float4 v  = *(const float4*)&st[slot * SLOT_DW + row * 4];
            const long bb   = wbat0 + (slot >> 3);
            const int  fr   = 4 * (slot & 7) + j;
            if (bb < (long)B)
                out4[bb * 128 + fr * 4 + row] = v;   // 4-lane cluster = 1 full line
        }
        __builtin_amdgcn_wave_barrier();
    }
}

extern "C" void kernel_launch(void* const* d_in, const int* in_sizes, int n_in,
                              void* d_out, int out_size, void* d_ws, size_t ws_size,
                              hipStream_t stream) {
    const float* ja   = (const float*)d_in[0];
    const float* axes = (const float*)d_in[1];
    const float* orig = (const float*)d_in[2];
    const float* mmul = (const float*)d_in[3];
    const float* moff = (const float*)d_in[4];
    const int*   ctrl = (const int*)d_in[5];
    const int*   msrc = (const int*)d_in[6];
    const int*   mdst = (const int*)d_in[7];
    const int*   typs = (const int*)d_in[8];
    float* out = (float*)d_out;

    const int B = in_sizes[0] / NDOF;
    const int grid = (B + 31) / 32;     // 32 batches per block (8 lanes/batch)
    fk_kernel<<<grid, BLOCK, 0, stream>>>(ja, axes, orig, mmul, moff,
                                          ctrl, msrc, mdst, typs, out, B);
}